// Round 8
// baseline (292.484 us; speedup 1.0000x reference)
//
#include <hip/hip_runtime.h>
#include <math.h>

#define NH 12
#define DM 768
#define HD 64
#define BB 4
#define TT 2048
#define MTOT (BB*TT)   // 8192

// 1/sqrt(64) * log2(e) — folded into Q at the QKV-GEMM epilogue
#define QSCALE 0.1803368801111204f

typedef short bf16x8 __attribute__((ext_vector_type(8)));
typedef float f32x4 __attribute__((ext_vector_type(4)));
typedef int   i32x4 __attribute__((ext_vector_type(4)));
typedef unsigned int u32;

#define GLDS(g, l) __builtin_amdgcn_global_load_lds((const __attribute__((address_space(1))) u32*)(g), (__attribute__((address_space(3))) u32*)(l), 16, 0, 0)

__device__ __forceinline__ unsigned short f2bf(float f) {
    unsigned u = __float_as_uint(f);
    u += 0x7fff + ((u >> 16) & 1);   // RNE
    return (unsigned short)(u >> 16);
}

// ---------------- fused prep: pack_x + pack_wqkv + pack_wo + bias_o ----------------
__global__ void k_prep(const float* __restrict__ x,
                       const float* __restrict__ Wq, const float* __restrict__ Wk,
                       const float* __restrict__ Wv, const float* __restrict__ Wo,
                       const float* __restrict__ bo, const float* __restrict__ gate,
                       unsigned short* __restrict__ xb, unsigned short* __restrict__ wqkv,
                       unsigned short* __restrict__ wob, float* __restrict__ bio)
{
    __shared__ unsigned short L[64][72];
    const int bid = blockIdx.x;
    if (bid < 6144) {
        int i = (bid * 256 + threadIdx.x) * 4;
        float4 v = *(const float4*)(x + i);
        ushort4 o = { f2bf(v.x), f2bf(v.y), f2bf(v.z), f2bf(v.w) };
        *(ushort4*)(xb + i) = o;
    } else if (bid < 6576) {
        int b2 = bid - 6144;                 // 432 blocks: q(3) x h(12) x kd-tile(12)
        int q = b2 / 144, r = b2 % 144, h = r / 12, kt = r % 12;
        const float* W = (q == 0 ? Wq : (q == 1 ? Wk : Wv)) + (size_t)h * DM * HD + (size_t)kt * 64 * HD;
        #pragma unroll
        for (int it = 0; it < 4; it++) {
            int idx = it * 256 + threadIdx.x;
            int rr = idx >> 4, e4 = (idx & 15) * 4;
            float4 v = *(const float4*)&W[(size_t)rr * HD + e4];
            L[e4    ][rr] = f2bf(v.x);
            L[e4 + 1][rr] = f2bf(v.y);
            L[e4 + 2][rr] = f2bf(v.z);
            L[e4 + 3][rr] = f2bf(v.w);
        }
        __syncthreads();
        #pragma unroll
        for (int it = 0; it < 2; it++) {
            int idx = it * 256 + threadIdx.x;
            int e = idx >> 3, c8 = (idx & 7) * 8;
            *(bf16x8*)&wqkv[(size_t)(q * 768 + h * 64 + e) * DM + kt * 64 + c8] = *(const bf16x8*)&L[e][c8];
        }
    } else if (bid < 6720) {
        int b2 = bid - 6576;                 // 144 blocks: head(12) x d-tile(12)
        int ht = b2 / 12, dt = b2 % 12;
        float g = gate[ht]; g = (g < 1e-6f) ? 0.f : g;
        const float* W = Wo + (size_t)ht * 64 * DM + dt * 64;
        #pragma unroll
        for (int it = 0; it < 4; it++) {
            int idx = it * 256 + threadIdx.x;
            int rr = idx >> 4, d4 = (idx & 15) * 4;
            float4 v = *(const float4*)&W[(size_t)rr * DM + d4];
            L[d4    ][rr] = f2bf(g * v.x);
            L[d4 + 1][rr] = f2bf(g * v.y);
            L[d4 + 2][rr] = f2bf(g * v.z);
            L[d4 + 3][rr] = f2bf(g * v.w);
        }
        __syncthreads();
        #pragma unroll
        for (int it = 0; it < 2; it++) {
            int idx = it * 256 + threadIdx.x;
            int d = idx >> 3, c8 = (idx & 7) * 8;
            *(bf16x8*)&wob[(size_t)(dt * 64 + d) * DM + ht * 64 + c8] = *(const bf16x8*)&L[d][c8];
        }
    } else {
        int d = (bid - 6720) * 256 + threadIdx.x;
        if (d < DM) {
            float s = 0.f;
            #pragma unroll
            for (int h = 0; h < NH; h++) {
                float g = gate[h]; g = (g < 1e-6f) ? 0.f : g;
                s += g * bo[h * DM + d];
            }
            bio[d] = s;
        }
    }
}

// ---------------- GEMM: QKV projection (GLDS-staged, double-buffered) ----------------
__global__ __launch_bounds__(256) void k_gemm_qkv(
    const unsigned short* __restrict__ A,
    const unsigned short* __restrict__ Bt,
    const float* __restrict__ bq, const float* __restrict__ bk, const float* __restrict__ bv,
    unsigned short* __restrict__ Q, unsigned short* __restrict__ Kg, unsigned short* __restrict__ Vt)
{
    __shared__ unsigned short As[2][4096];
    __shared__ unsigned short Bs[2][4096];
    const int m0 = blockIdx.y * 128, n0 = blockIdx.x * 128;
    const int tid = threadIdx.x, lane = tid & 63, w = tid >> 6;
    const int wr = (w >> 1) * 64, wc = (w & 1) * 64;
    const int lr = lane & 15, lq = lane >> 4;

    const int arow = tid >> 2;
    const int ag   = ((tid & 3) ^ (arow & 3)) * 8;
    const int ldsw = w * 512;
    const int kg = (lq ^ (lr & 3)) * 8;

    #define STAGE_G(k0_, buf_) do { \
        const unsigned short* a_ = A  + (size_t)(m0 + arow) * DM + (k0_) + ag; \
        const unsigned short* b_ = Bt + (size_t)(n0 + arow) * DM + (k0_) + ag; \
        GLDS(a_,             &As[buf_][ldsw]); \
        GLDS(a_ + 64 * DM,   &As[buf_][2048 + ldsw]); \
        GLDS(b_,             &Bs[buf_][ldsw]); \
        GLDS(b_ + 64 * DM,   &Bs[buf_][2048 + ldsw]); \
    } while (0)

    f32x4 acc[4][4] = {};
    STAGE_G(0, 0);
    for (int it = 0; it < DM / 32; it++) {
        const int cur = it & 1;
        __syncthreads();
        if (it < DM / 32 - 1) STAGE_G((it + 1) * 32, cur ^ 1);
        bf16x8 af[4], bf[4];
        #pragma unroll
        for (int rt = 0; rt < 4; rt++) af[rt] = *(const bf16x8*)&As[cur][(wr + rt*16 + lr) * 32 + kg];
        #pragma unroll
        for (int ct = 0; ct < 4; ct++) bf[ct] = *(const bf16x8*)&Bs[cur][(wc + ct*16 + lr) * 32 + kg];
        #pragma unroll
        for (int rt = 0; rt < 4; rt++)
            #pragma unroll
            for (int ct = 0; ct < 4; ct++)
                acc[rt][ct] = __builtin_amdgcn_mfma_f32_16x16x32_bf16(af[rt], bf[ct], acc[rt][ct], 0, 0, 0);
    }
    #undef STAGE_G

    const int region = n0 / DM;          // 0=Q 1=K 2=V
    const int b  = m0 >> 11;
    const int tb = m0 & 2047;
    if (region == 2) {
        #pragma unroll
        for (int rt = 0; rt < 4; rt++)
          #pragma unroll
          for (int ct = 0; ct < 4; ct++) {
            int n = n0 + wc + ct*16 + lr, r = n - 2*DM;
            int h = r >> 6, e = r & 63;
            int t0 = tb + wr + rt*16 + lq*4;
            float bias = bv[r];
            ushort4 o;
            o.x = f2bf(acc[rt][ct][0] + bias);
            o.y = f2bf(acc[rt][ct][1] + bias);
            o.z = f2bf(acc[rt][ct][2] + bias);
            o.w = f2bf(acc[rt][ct][3] + bias);
            *(ushort4*)&Vt[((size_t)(b*NH + h)*HD + e)*TT + t0] = o;
          }
    } else {
        const float* bias_p = (region == 0) ? bq : bk;
        const float  scale  = (region == 0) ? QSCALE : 1.0f;
        unsigned short* dst = (region == 0) ? Q : Kg;
        #pragma unroll
        for (int rt = 0; rt < 4; rt++)
          #pragma unroll
          for (int ct = 0; ct < 4; ct++) {
            int n = n0 + wc + ct*16 + lr, r = n - region*DM;
            int h = r >> 6, e = r & 63;
            float bias = bias_p[r];
            #pragma unroll
            for (int i = 0; i < 4; i++) {
                int t = tb + wr + rt*16 + lq*4 + i;
                dst[((size_t)(b*NH + h)*TT + t)*HD + e] = f2bf((acc[rt][ct][i] + bias) * scale);
            }
          }
    }
}

// ---------------- Flash attention v6: R6 geometry + distance-2 prefetch ----------------
// 32 q/wave, KV-tile 64, 32 iters. THREE LDS buffers, STAGE(kt+2) in flight;
// sync is raw `s_waitcnt vmcnt(4); s_barrier` (waits only own tile-kt loads,
// leaves tile-(kt+1)'s 4 GLDS outstanding across the barrier) instead of
// __syncthreads' compiler-forced vmcnt(0) drain — the m97 structural stall.
// Hazards: RAW via own-drain+barrier; WAR: buf (kt+2)%3 last read iter kt-1,
// reads complete before the barrier just crossed.
__global__ __launch_bounds__(256) void k_flash(
    const unsigned short* __restrict__ Q, const unsigned short* __restrict__ Kg,
    const unsigned short* __restrict__ Vt, unsigned short* __restrict__ A2)
{
    __shared__ unsigned short Ks[3][4096];   // [buf][row*64 + f8'*8]
    __shared__ unsigned short Vs[3][4096];
    const int bh = blockIdx.x, qt = blockIdx.y;
    const int b = bh / NH, h = bh % NH;
    const int tid = threadIdx.x, lane = tid & 63, w = tid >> 6;
    const int col = lane & 15, quad = lane >> 4;
    const size_t qk_base = (size_t)bh * TT * HD;
    const size_t vt_base = (size_t)bh * HD * TT;
    const int tq0 = qt * 128 + w * 32;

    const int srow  = tid >> 3;
    const int sperm = (tid & 7) ^ (srow & 7);
    const int koff0 = srow * HD + sperm * 8;
    const int voff0 = srow * TT + sperm * 8;
    const int lds0  = w * 512;

    const unsigned short* ksrc = Kg + qk_base;
    const unsigned short* vsrc = Vt + vt_base;

    const int c7 = col & 7;
    const int ra0 = col * 64 + (((    quad) ^ c7) * 8);
    const int ra1 = col * 64 + (((4 + quad) ^ c7) * 8);

    bf16x8 aq[2][2];
    #pragma unroll
    for (int rt = 0; rt < 2; rt++)
        #pragma unroll
        for (int ks = 0; ks < 2; ks++)
            aq[rt][ks] = *(const bf16x8*)&Q[qk_base + (size_t)(tq0 + rt*16 + col) * HD + ks*32 + quad*8];

    f32x4 co[4][2] = {};
    float l_part[2] = { 0.f, 0.f };

    const int srcA = (((quad * 2    ) & 3) << 4) | col;
    const int srcB = (((quad * 2 + 1) & 3) << 4) | col;

    #define STAGE(kt_, buf_) do { \
        const unsigned short* kb_ = ksrc + (size_t)(kt_) * 64 * HD; \
        const unsigned short* vb_ = vsrc + (kt_) * 64; \
        GLDS(kb_ + koff0,           &Ks[buf_][lds0]); \
        GLDS(kb_ + koff0 + 32*HD,   &Ks[buf_][lds0 + 2048]); \
        GLDS(vb_ + voff0,           &Vs[buf_][lds0]); \
        GLDS(vb_ + voff0 + 32*TT,   &Vs[buf_][lds0 + 2048]); \
    } while (0)

    STAGE(0, 0);
    STAGE(1, 1);

    const int NIT = TT / 64;
    for (int kt = 0; kt < NIT; kt++) {
        const int cur = kt % 3;
        // own tile-kt loads drained (4 newest = tile kt+1 stay in flight),
        // then rendezvous: all waves' tile-kt data resident.
        if (kt == NIT - 1) asm volatile("s_waitcnt vmcnt(0)" ::: "memory");
        else               asm volatile("s_waitcnt vmcnt(4)" ::: "memory");
        asm volatile("s_barrier" ::: "memory");
        if (kt < NIT - 2) STAGE(kt + 2, (kt + 2) % 3);

        bf16x8 kf[4][2];
        #pragma unroll
        for (int ct = 0; ct < 4; ct++) {
            kf[ct][0] = *(const bf16x8*)&Ks[cur][ct*1024 + ra0];
            kf[ct][1] = *(const bf16x8*)&Ks[cur][ct*1024 + ra1];
        }

        f32x4 cs[4][2] = {};
        #pragma unroll
        for (int ks = 0; ks < 2; ks++)
            #pragma unroll
            for (int ct = 0; ct < 4; ct++)
                #pragma unroll
                for (int rt = 0; rt < 2; rt++)
                    cs[ct][rt] = __builtin_amdgcn_mfma_f32_16x16x32_bf16(kf[ct][ks], aq[rt][ks], cs[ct][rt], 0, 0, 0);

        int pk[2][4][2];
        #pragma unroll
        for (int rt = 0; rt < 2; rt++) {
            float ps[4][4];
            float ssum = 0.f;
            #pragma unroll
            for (int ct = 0; ct < 4; ct++)
                #pragma unroll
                for (int i = 0; i < 4; i++) {
                    float p = __builtin_amdgcn_exp2f(cs[ct][rt][i]);
                    ps[ct][i] = p;
                    ssum += p;
                }
            l_part[rt] += ssum;
            #pragma unroll
            for (int ct = 0; ct < 4; ct++) {
                pk[rt][ct][0] = (int)__builtin_amdgcn_perm(__float_as_uint(ps[ct][1]), __float_as_uint(ps[ct][0]), 0x07060302u);
                pk[rt][ct][1] = (int)__builtin_amdgcn_perm(__float_as_uint(ps[ct][3]), __float_as_uint(ps[ct][2]), 0x07060302u);
            }
        }

        #pragma unroll
        for (int k4 = 0; k4 < 2; k4++) {
            bf16x8 pt[2];
            #pragma unroll
            for (int rt = 0; rt < 2; rt++) {
                int a0 = __shfl(pk[rt][2*k4  ][0], srcA);
                int b0 = __shfl(pk[rt][2*k4+1][0], srcA);
                int a1 = __shfl(pk[rt][2*k4  ][1], srcA);
                int b1 = __shfl(pk[rt][2*k4+1][1], srcA);
                int a2 = __shfl(pk[rt][2*k4  ][0], srcB);
                int b2 = __shfl(pk[rt][2*k4+1][0], srcB);
                int a3 = __shfl(pk[rt][2*k4  ][1], srcB);
                int b3 = __shfl(pk[rt][2*k4+1][1], srcB);
                i32x4 di;
                di[0] = (quad < 2) ? a0 : b0;
                di[1] = (quad < 2) ? a1 : b1;
                di[2] = (quad < 2) ? a2 : b2;
                di[3] = (quad < 2) ? a3 : b3;
                pt[rt] = __builtin_bit_cast(bf16x8, di);
            }
            const int rav = (k4 == 0) ? ra0 : ra1;
            #pragma unroll
            for (int cv = 0; cv < 4; cv++) {
                bf16x8 vf = *(const bf16x8*)&Vs[cur][cv*1024 + rav];
                #pragma unroll
                for (int rt = 0; rt < 2; rt++)
                    co[cv][rt] = __builtin_amdgcn_mfma_f32_16x16x32_bf16(vf, pt[rt], co[cv][rt], 0, 0, 0);
            }
        }
    }
    #undef STAGE

    #pragma unroll
    for (int rt = 0; rt < 2; rt++) {
        float l = l_part[rt];
        l += __shfl_xor(l, 16);
        l += __shfl_xor(l, 32);
        float inv = 1.0f / l;
        int t = tq0 + rt*16 + col;
        #pragma unroll
        for (int cv = 0; cv < 4; cv++) {
            ushort4 o;
            o.x = f2bf(co[cv][rt][0] * inv);
            o.y = f2bf(co[cv][rt][1] * inv);
            o.z = f2bf(co[cv][rt][2] * inv);
            o.w = f2bf(co[cv][rt][3] * inv);
            *(ushort4*)&A2[(size_t)(b*TT + t) * DM + h*HD + cv*16 + quad*4] = o;
        }
    }
}

// ---------------- GEMM: output projection (GLDS-staged) ----------------
__global__ __launch_bounds__(256) void k_gemm_out(
    const unsigned short* __restrict__ A,
    const unsigned short* __restrict__ Bt,
    const float* __restrict__ bias,
    float* __restrict__ out)
{
    __shared__ unsigned short As[2][4096];
    __shared__ unsigned short Bs[2][4096];
    const int m0 = blockIdx.y * 128, n0 = blockIdx.x * 128;
    const int tid = threadIdx.x, lane = tid & 63, w = tid >> 6;
    const int wr = (w >> 1) * 64, wc = (w & 1) * 64;
    const int lr = lane & 15, lq = lane >> 4;

    const int arow = tid >> 2;
    const int ag   = ((tid & 3) ^ (arow & 3)) * 8;
    const int ldsw = w * 512;
    const int kg = (lq ^ (lr & 3)) * 8;

    #define STAGE_G(k0_, buf_) do { \
        const unsigned short* a_ = A  + (size_t)(m0 + arow) * DM + (k0_) + ag; \
        const unsigned short* b_ = Bt + (size_t)(n0 + arow) * DM + (k0_) + ag; \
        GLDS(a_,             &As[buf_][ldsw]); \
        GLDS(a_ + 64 * DM,   &As[buf_][2048 + ldsw]); \
        GLDS(b_,             &Bs[buf_][ldsw]); \
        GLDS(b_ + 64 * DM,   &Bs[buf_][2048 + ldsw]); \
    } while (0)

    f32x4 acc[4][4] = {};
    STAGE_G(0, 0);
    for (int it = 0; it < DM / 32; it++) {
        const int cur = it & 1;
        __syncthreads();
        if (it < DM / 32 - 1) STAGE_G((it + 1) * 32, cur ^ 1);
        bf16x8 af[4], bf[4];
        #pragma unroll
        for (int rt = 0; rt < 4; rt++) af[rt] = *(const bf16x8*)&As[cur][(wr + rt*16 + lr) * 32 + kg];
        #pragma unroll
        for (int ct = 0; ct < 4; ct++) bf[ct] = *(const bf16x8*)&Bs[cur][(wc + ct*16 + lr) * 32 + kg];
        #pragma unroll
        for (int rt = 0; rt < 4; rt++)
            #pragma unroll
            for (int ct = 0; ct < 4; ct++)
                acc[rt][ct] = __builtin_amdgcn_mfma_f32_16x16x32_bf16(af[rt], bf[ct], acc[rt][ct], 0, 0, 0);
    }
    #undef STAGE_G

    #pragma unroll
    for (int rt = 0; rt < 4; rt++)
      #pragma unroll
      for (int ct = 0; ct < 4; ct++)
        #pragma unroll
        for (int i = 0; i < 4; i++) {
            int m = m0 + wr + rt*16 + lq*4 + i;
            int n = n0 + wc + ct*16 + lr;
            out[(size_t)m * DM + n] = acc[rt][ct][i] + bias[n];
        }
}

// ---------------- launcher ----------------
extern "C" void kernel_launch(void* const* d_in, const int* in_sizes, int n_in,
                              void* d_out, int out_size, void* d_ws, size_t ws_size,
                              hipStream_t stream) {
    const float* x    = (const float*)d_in[0];
    const float* Wq   = (const float*)d_in[1];
    const float* bq   = (const float*)d_in[2];
    const float* Wk   = (const float*)d_in[3];
    const float* bk   = (const float*)d_in[4];
    const float* Wv   = (const float*)d_in[5];
    const float* bv   = (const float*)d_in[6];
    const float* Wo   = (const float*)d_in[7];
    const float* bo   = (const float*)d_in[8];
    const float* gate = (const float*)d_in[9];
    float* out = (float*)d_out;

    char* p = (char*)d_ws;
    unsigned short* Xb   = (unsigned short*)p;  p += (size_t)MTOT*DM*2;
    unsigned short* Wqkv = (unsigned short*)p;  p += (size_t)3*DM*DM*2;
    unsigned short* Qb   = (unsigned short*)p;  p += (size_t)BB*NH*TT*HD*2;
    unsigned short* Kb   = (unsigned short*)p;  p += (size_t)BB*NH*TT*HD*2;
    unsigned short* Vtb  = (unsigned short*)p;  p += (size_t)BB*NH*TT*HD*2;
    unsigned short* A2   = (unsigned short*)p;  p += (size_t)MTOT*DM*2;
    unsigned short* Wob  = (unsigned short*)p;  p += (size_t)DM*DM*2;
    float*          bio  = (float*)p;           p += (size_t)DM*4;

    k_prep     <<<6723, 256, 0, stream>>>(x, Wq, Wk, Wv, Wo, bo, gate, Xb, Wqkv, Wob, bio);
    k_gemm_qkv <<<dim3((3*DM)/128, MTOT/128), 256, 0, stream>>>(Xb, Wqkv, bq, bk, bv, Qb, Kb, Vtb);
    k_flash    <<<dim3(BB*NH, TT/128), 256, 0, stream>>>(Qb, Kb, Vtb, A2);
    k_gemm_out <<<dim3(DM/128, MTOT/128), 256, 0, stream>>>(A2, Wob, bio, out);
}

// Round 9
// 285.614 us; speedup vs baseline: 1.0241x; 1.0241x over previous
//
#include <hip/hip_runtime.h>
#include <math.h>

#define NH 12
#define DM 768
#define HD 64
#define BB 4
#define TT 2048
#define MTOT (BB*TT)   // 8192

#define OP_STRIDE ((size_t)MTOT * DM)      // fp32 partial-O per split
#define LP_STRIDE ((size_t)BB * NH * TT)   // fp32 partial-l per split

// 1/sqrt(64) * log2(e) — folded into Q at the QKV-GEMM epilogue
#define QSCALE 0.1803368801111204f

typedef short bf16x8 __attribute__((ext_vector_type(8)));
typedef float f32x4 __attribute__((ext_vector_type(4)));
typedef int   i32x4 __attribute__((ext_vector_type(4)));
typedef unsigned int u32;

#define GLDS(g, l) __builtin_amdgcn_global_load_lds((const __attribute__((address_space(1))) u32*)(g), (__attribute__((address_space(3))) u32*)(l), 16, 0, 0)

__device__ __forceinline__ unsigned short f2bf(float f) {
    unsigned u = __float_as_uint(f);
    u += 0x7fff + ((u >> 16) & 1);   // RNE
    return (unsigned short)(u >> 16);
}

// ---------------- fused prep: pack_x + pack_wqkv + pack_wo + bias_o ----------------
__global__ void k_prep(const float* __restrict__ x,
                       const float* __restrict__ Wq, const float* __restrict__ Wk,
                       const float* __restrict__ Wv, const float* __restrict__ Wo,
                       const float* __restrict__ bo, const float* __restrict__ gate,
                       unsigned short* __restrict__ xb, unsigned short* __restrict__ wqkv,
                       unsigned short* __restrict__ wob, float* __restrict__ bio)
{
    __shared__ unsigned short L[64][72];
    const int bid = blockIdx.x;
    if (bid < 6144) {
        int i = (bid * 256 + threadIdx.x) * 4;
        float4 v = *(const float4*)(x + i);
        ushort4 o = { f2bf(v.x), f2bf(v.y), f2bf(v.z), f2bf(v.w) };
        *(ushort4*)(xb + i) = o;
    } else if (bid < 6576) {
        int b2 = bid - 6144;                 // 432 blocks: q(3) x h(12) x kd-tile(12)
        int q = b2 / 144, r = b2 % 144, h = r / 12, kt = r % 12;
        const float* W = (q == 0 ? Wq : (q == 1 ? Wk : Wv)) + (size_t)h * DM * HD + (size_t)kt * 64 * HD;
        #pragma unroll
        for (int it = 0; it < 4; it++) {
            int idx = it * 256 + threadIdx.x;
            int rr = idx >> 4, e4 = (idx & 15) * 4;
            float4 v = *(const float4*)&W[(size_t)rr * HD + e4];
            L[e4    ][rr] = f2bf(v.x);
            L[e4 + 1][rr] = f2bf(v.y);
            L[e4 + 2][rr] = f2bf(v.z);
            L[e4 + 3][rr] = f2bf(v.w);
        }
        __syncthreads();
        #pragma unroll
        for (int it = 0; it < 2; it++) {
            int idx = it * 256 + threadIdx.x;
            int e = idx >> 3, c8 = (idx & 7) * 8;
            *(bf16x8*)&wqkv[(size_t)(q * 768 + h * 64 + e) * DM + kt * 64 + c8] = *(const bf16x8*)&L[e][c8];
        }
    } else if (bid < 6720) {
        int b2 = bid - 6576;                 // 144 blocks: head(12) x d-tile(12)
        int ht = b2 / 12, dt = b2 % 12;
        float g = gate[ht]; g = (g < 1e-6f) ? 0.f : g;
        const float* W = Wo + (size_t)ht * 64 * DM + dt * 64;
        #pragma unroll
        for (int it = 0; it < 4; it++) {
            int idx = it * 256 + threadIdx.x;
            int rr = idx >> 4, d4 = (idx & 15) * 4;
            float4 v = *(const float4*)&W[(size_t)rr * DM + d4];
            L[d4    ][rr] = f2bf(g * v.x);
            L[d4 + 1][rr] = f2bf(g * v.y);
            L[d4 + 2][rr] = f2bf(g * v.z);
            L[d4 + 3][rr] = f2bf(g * v.w);
        }
        __syncthreads();
        #pragma unroll
        for (int it = 0; it < 2; it++) {
            int idx = it * 256 + threadIdx.x;
            int d = idx >> 3, c8 = (idx & 7) * 8;
            *(bf16x8*)&wob[(size_t)(dt * 64 + d) * DM + ht * 64 + c8] = *(const bf16x8*)&L[d][c8];
        }
    } else {
        int d = (bid - 6720) * 256 + threadIdx.x;
        if (d < DM) {
            float s = 0.f;
            #pragma unroll
            for (int h = 0; h < NH; h++) {
                float g = gate[h]; g = (g < 1e-6f) ? 0.f : g;
                s += g * bo[h * DM + d];
            }
            bio[d] = s;
        }
    }
}

// ---------------- GEMM: QKV projection (GLDS-staged, double-buffered) ----------------
__global__ __launch_bounds__(256) void k_gemm_qkv(
    const unsigned short* __restrict__ A,
    const unsigned short* __restrict__ Bt,
    const float* __restrict__ bq, const float* __restrict__ bk, const float* __restrict__ bv,
    unsigned short* __restrict__ Q, unsigned short* __restrict__ Kg, unsigned short* __restrict__ Vt)
{
    __shared__ unsigned short As[2][4096];
    __shared__ unsigned short Bs[2][4096];
    const int m0 = blockIdx.y * 128, n0 = blockIdx.x * 128;
    const int tid = threadIdx.x, lane = tid & 63, w = tid >> 6;
    const int wr = (w >> 1) * 64, wc = (w & 1) * 64;
    const int lr = lane & 15, lq = lane >> 4;

    const int arow = tid >> 2;
    const int ag   = ((tid & 3) ^ (arow & 3)) * 8;
    const int ldsw = w * 512;
    const int kg = (lq ^ (lr & 3)) * 8;

    #define STAGE_G(k0_, buf_) do { \
        const unsigned short* a_ = A  + (size_t)(m0 + arow) * DM + (k0_) + ag; \
        const unsigned short* b_ = Bt + (size_t)(n0 + arow) * DM + (k0_) + ag; \
        GLDS(a_,             &As[buf_][ldsw]); \
        GLDS(a_ + 64 * DM,   &As[buf_][2048 + ldsw]); \
        GLDS(b_,             &Bs[buf_][ldsw]); \
        GLDS(b_ + 64 * DM,   &Bs[buf_][2048 + ldsw]); \
    } while (0)

    f32x4 acc[4][4] = {};
    STAGE_G(0, 0);
    for (int it = 0; it < DM / 32; it++) {
        const int cur = it & 1;
        __syncthreads();
        if (it < DM / 32 - 1) STAGE_G((it + 1) * 32, cur ^ 1);
        bf16x8 af[4], bf[4];
        #pragma unroll
        for (int rt = 0; rt < 4; rt++) af[rt] = *(const bf16x8*)&As[cur][(wr + rt*16 + lr) * 32 + kg];
        #pragma unroll
        for (int ct = 0; ct < 4; ct++) bf[ct] = *(const bf16x8*)&Bs[cur][(wc + ct*16 + lr) * 32 + kg];
        #pragma unroll
        for (int rt = 0; rt < 4; rt++)
            #pragma unroll
            for (int ct = 0; ct < 4; ct++)
                acc[rt][ct] = __builtin_amdgcn_mfma_f32_16x16x32_bf16(af[rt], bf[ct], acc[rt][ct], 0, 0, 0);
    }
    #undef STAGE_G

    const int region = n0 / DM;          // 0=Q 1=K 2=V
    const int b  = m0 >> 11;
    const int tb = m0 & 2047;
    if (region == 2) {
        #pragma unroll
        for (int rt = 0; rt < 4; rt++)
          #pragma unroll
          for (int ct = 0; ct < 4; ct++) {
            int n = n0 + wc + ct*16 + lr, r = n - 2*DM;
            int h = r >> 6, e = r & 63;
            int t0 = tb + wr + rt*16 + lq*4;
            float bias = bv[r];
            ushort4 o;
            o.x = f2bf(acc[rt][ct][0] + bias);
            o.y = f2bf(acc[rt][ct][1] + bias);
            o.z = f2bf(acc[rt][ct][2] + bias);
            o.w = f2bf(acc[rt][ct][3] + bias);
            *(ushort4*)&Vt[((size_t)(b*NH + h)*HD + e)*TT + t0] = o;
          }
    } else {
        const float* bias_p = (region == 0) ? bq : bk;
        const float  scale  = (region == 0) ? QSCALE : 1.0f;
        unsigned short* dst = (region == 0) ? Q : Kg;
        #pragma unroll
        for (int rt = 0; rt < 4; rt++)
          #pragma unroll
          for (int ct = 0; ct < 4; ct++) {
            int n = n0 + wc + ct*16 + lr, r = n - region*DM;
            int h = r >> 6, e = r & 63;
            float bias = bias_p[r];
            #pragma unroll
            for (int i = 0; i < 4; i++) {
                int t = tb + wr + rt*16 + lq*4 + i;
                dst[((size_t)(b*NH + h)*TT + t)*HD + e] = f2bf((acc[rt][ct][i] + bias) * scale);
            }
          }
    }
}

// ---------------- Flash attention v7: R6 structure + KV-split 2 ----------------
// grid (48, 16, 2): split sp handles kv tiles [sp*16, sp*16+16). 1536 blocks
// -> 5 blocks/CU (LDS cap), 20 waves/CU = 1.67x R6 TLP with identical
// per-iteration chain. No-max softmax is associative across splits: block
// writes UNNORMALIZED fp32 O-partial + l-partial; k_comb merges.
__global__ __launch_bounds__(256) void k_flash(
    const unsigned short* __restrict__ Q, const unsigned short* __restrict__ Kg,
    const unsigned short* __restrict__ Vt, float* __restrict__ Op, float* __restrict__ lp)
{
    __shared__ unsigned short Ks[2][4096];   // [buf][row*64 + f8'*8]
    __shared__ unsigned short Vs[2][4096];
    const int bh = blockIdx.x, qt = blockIdx.y, sp = blockIdx.z;
    const int b = bh / NH, h = bh % NH;
    const int tid = threadIdx.x, lane = tid & 63, w = tid >> 6;
    const int col = lane & 15, quad = lane >> 4;
    const size_t qk_base = (size_t)bh * TT * HD;
    const size_t vt_base = (size_t)bh * HD * TT;
    const int tq0 = qt * 128 + w * 32;
    const int kt0 = sp * 16;                 // 16 kv-tiles of 64 per split

    const int srow  = tid >> 3;
    const int sperm = (tid & 7) ^ (srow & 7);
    const int koff0 = srow * HD + sperm * 8;
    const int voff0 = srow * TT + sperm * 8;
    const int lds0  = w * 512;

    const unsigned short* ksrc = Kg + qk_base;
    const unsigned short* vsrc = Vt + vt_base;

    const int c7 = col & 7;
    const int ra0 = col * 64 + (((    quad) ^ c7) * 8);
    const int ra1 = col * 64 + (((4 + quad) ^ c7) * 8);

    bf16x8 aq[2][2];
    #pragma unroll
    for (int rt = 0; rt < 2; rt++)
        #pragma unroll
        for (int ks = 0; ks < 2; ks++)
            aq[rt][ks] = *(const bf16x8*)&Q[qk_base + (size_t)(tq0 + rt*16 + col) * HD + ks*32 + quad*8];

    f32x4 co[4][2] = {};
    float l_part[2] = { 0.f, 0.f };

    const int srcA = (((quad * 2    ) & 3) << 4) | col;
    const int srcB = (((quad * 2 + 1) & 3) << 4) | col;

    #define STAGE(kt_, buf_) do { \
        const unsigned short* kb_ = ksrc + (size_t)(kt_) * 64 * HD; \
        const unsigned short* vb_ = vsrc + (kt_) * 64; \
        GLDS(kb_ + koff0,           &Ks[buf_][lds0]); \
        GLDS(kb_ + koff0 + 32*HD,   &Ks[buf_][lds0 + 2048]); \
        GLDS(vb_ + voff0,           &Vs[buf_][lds0]); \
        GLDS(vb_ + voff0 + 32*TT,   &Vs[buf_][lds0 + 2048]); \
    } while (0)

    STAGE(kt0, 0);

    for (int it = 0; it < 16; it++) {
        const int cur = it & 1;
        __syncthreads();
        if (it < 15) STAGE(kt0 + it + 1, cur ^ 1);

        bf16x8 kf[4][2];
        #pragma unroll
        for (int ct = 0; ct < 4; ct++) {
            kf[ct][0] = *(const bf16x8*)&Ks[cur][ct*1024 + ra0];
            kf[ct][1] = *(const bf16x8*)&Ks[cur][ct*1024 + ra1];
        }

        f32x4 cs[4][2] = {};
        #pragma unroll
        for (int ks = 0; ks < 2; ks++)
            #pragma unroll
            for (int ct = 0; ct < 4; ct++)
                #pragma unroll
                for (int rt = 0; rt < 2; rt++)
                    cs[ct][rt] = __builtin_amdgcn_mfma_f32_16x16x32_bf16(kf[ct][ks], aq[rt][ks], cs[ct][rt], 0, 0, 0);

        int pk[2][4][2];
        #pragma unroll
        for (int rt = 0; rt < 2; rt++) {
            float ps[4][4];
            float ssum = 0.f;
            #pragma unroll
            for (int ct = 0; ct < 4; ct++)
                #pragma unroll
                for (int i = 0; i < 4; i++) {
                    float p = __builtin_amdgcn_exp2f(cs[ct][rt][i]);
                    ps[ct][i] = p;
                    ssum += p;
                }
            l_part[rt] += ssum;
            #pragma unroll
            for (int ct = 0; ct < 4; ct++) {
                pk[rt][ct][0] = (int)__builtin_amdgcn_perm(__float_as_uint(ps[ct][1]), __float_as_uint(ps[ct][0]), 0x07060302u);
                pk[rt][ct][1] = (int)__builtin_amdgcn_perm(__float_as_uint(ps[ct][3]), __float_as_uint(ps[ct][2]), 0x07060302u);
            }
        }

        #pragma unroll
        for (int k4 = 0; k4 < 2; k4++) {
            bf16x8 pt[2];
            #pragma unroll
            for (int rt = 0; rt < 2; rt++) {
                int a0 = __shfl(pk[rt][2*k4  ][0], srcA);
                int b0 = __shfl(pk[rt][2*k4+1][0], srcA);
                int a1 = __shfl(pk[rt][2*k4  ][1], srcA);
                int b1 = __shfl(pk[rt][2*k4+1][1], srcA);
                int a2 = __shfl(pk[rt][2*k4  ][0], srcB);
                int b2 = __shfl(pk[rt][2*k4+1][0], srcB);
                int a3 = __shfl(pk[rt][2*k4  ][1], srcB);
                int b3 = __shfl(pk[rt][2*k4+1][1], srcB);
                i32x4 di;
                di[0] = (quad < 2) ? a0 : b0;
                di[1] = (quad < 2) ? a1 : b1;
                di[2] = (quad < 2) ? a2 : b2;
                di[3] = (quad < 2) ? a3 : b3;
                pt[rt] = __builtin_bit_cast(bf16x8, di);
            }
            const int rav = (k4 == 0) ? ra0 : ra1;
            #pragma unroll
            for (int cv = 0; cv < 4; cv++) {
                bf16x8 vf = *(const bf16x8*)&Vs[cur][cv*1024 + rav];
                #pragma unroll
                for (int rt = 0; rt < 2; rt++)
                    co[cv][rt] = __builtin_amdgcn_mfma_f32_16x16x32_bf16(vf, pt[rt], co[cv][rt], 0, 0, 0);
            }
        }
    }
    #undef STAGE

    // epilogue: UNNORMALIZED fp32 partials + l per q-row
    float* op = Op + (size_t)sp * OP_STRIDE;
    #pragma unroll
    for (int rt = 0; rt < 2; rt++) {
        float l = l_part[rt];
        l += __shfl_xor(l, 16);
        l += __shfl_xor(l, 32);
        int t = tq0 + rt*16 + col;
        if (quad == 0)
            lp[(size_t)sp * LP_STRIDE + (size_t)bh * TT + t] = l;
        #pragma unroll
        for (int cv = 0; cv < 4; cv++) {
            float4 o = { co[cv][rt][0], co[cv][rt][1], co[cv][rt][2], co[cv][rt][3] };
            *(float4*)&op[(size_t)(b*TT + t) * DM + h*HD + cv*16 + quad*4] = o;
        }
    }
}

// ---------------- combine: A2 = (Op0 + Op1) / (l0 + l1), bf16 ----------------
__global__ __launch_bounds__(256) void k_comb(const float* __restrict__ Op,
                                              const float* __restrict__ lp,
                                              unsigned short* __restrict__ A2)
{
    const int bid = blockIdx.x;   // 2048 blocks x 4 rows
    #pragma unroll
    for (int rep = 0; rep < 3; rep++) {
        int idx = rep * 256 + threadIdx.x;       // 0..767
        int rl = idx / 192, c4 = idx % 192;
        int row = bid * 4 + rl;
        int b = row >> 11, t = row & 2047;
        int d = c4 * 4, h = d >> 6;
        size_t li = (size_t)(b*NH + h) * TT + t;
        float l = lp[li] + lp[LP_STRIDE + li];
        float inv = 1.0f / l;
        float4 o0 = *(const float4*)&Op[(size_t)row * DM + d];
        float4 o1 = *(const float4*)&Op[OP_STRIDE + (size_t)row * DM + d];
        ushort4 o;
        o.x = f2bf((o0.x + o1.x) * inv);
        o.y = f2bf((o0.y + o1.y) * inv);
        o.z = f2bf((o0.z + o1.z) * inv);
        o.w = f2bf((o0.w + o1.w) * inv);
        *(ushort4*)&A2[(size_t)row * DM + d] = o;
    }
}

// ---------------- GEMM: output projection (GLDS-staged) ----------------
__global__ __launch_bounds__(256) void k_gemm_out(
    const unsigned short* __restrict__ A,
    const unsigned short* __restrict__ Bt,
    const float* __restrict__ bias,
    float* __restrict__ out)
{
    __shared__ unsigned short As[2][4096];
    __shared__ unsigned short Bs[2][4096];
    const int m0 = blockIdx.y * 128, n0 = blockIdx.x * 128;
    const int tid = threadIdx.x, lane = tid & 63, w = tid >> 6;
    const int wr = (w >> 1) * 64, wc = (w & 1) * 64;
    const int lr = lane & 15, lq = lane >> 4;

    const int arow = tid >> 2;
    const int ag   = ((tid & 3) ^ (arow & 3)) * 8;
    const int ldsw = w * 512;
    const int kg = (lq ^ (lr & 3)) * 8;

    #define STAGE_G(k0_, buf_) do { \
        const unsigned short* a_ = A  + (size_t)(m0 + arow) * DM + (k0_) + ag; \
        const unsigned short* b_ = Bt + (size_t)(n0 + arow) * DM + (k0_) + ag; \
        GLDS(a_,             &As[buf_][ldsw]); \
        GLDS(a_ + 64 * DM,   &As[buf_][2048 + ldsw]); \
        GLDS(b_,             &Bs[buf_][ldsw]); \
        GLDS(b_ + 64 * DM,   &Bs[buf_][2048 + ldsw]); \
    } while (0)

    f32x4 acc[4][4] = {};
    STAGE_G(0, 0);
    for (int it = 0; it < DM / 32; it++) {
        const int cur = it & 1;
        __syncthreads();
        if (it < DM / 32 - 1) STAGE_G((it + 1) * 32, cur ^ 1);
        bf16x8 af[4], bf[4];
        #pragma unroll
        for (int rt = 0; rt < 4; rt++) af[rt] = *(const bf16x8*)&As[cur][(wr + rt*16 + lr) * 32 + kg];
        #pragma unroll
        for (int ct = 0; ct < 4; ct++) bf[ct] = *(const bf16x8*)&Bs[cur][(wc + ct*16 + lr) * 32 + kg];
        #pragma unroll
        for (int rt = 0; rt < 4; rt++)
            #pragma unroll
            for (int ct = 0; ct < 4; ct++)
                acc[rt][ct] = __builtin_amdgcn_mfma_f32_16x16x32_bf16(af[rt], bf[ct], acc[rt][ct], 0, 0, 0);
    }
    #undef STAGE_G

    #pragma unroll
    for (int rt = 0; rt < 4; rt++)
      #pragma unroll
      for (int ct = 0; ct < 4; ct++)
        #pragma unroll
        for (int i = 0; i < 4; i++) {
            int m = m0 + wr + rt*16 + lq*4 + i;
            int n = n0 + wc + ct*16 + lr;
            out[(size_t)m * DM + n] = acc[rt][ct][i] + bias[n];
        }
}

// ---------------- launcher ----------------
extern "C" void kernel_launch(void* const* d_in, const int* in_sizes, int n_in,
                              void* d_out, int out_size, void* d_ws, size_t ws_size,
                              hipStream_t stream) {
    const float* x    = (const float*)d_in[0];
    const float* Wq   = (const float*)d_in[1];
    const float* bq   = (const float*)d_in[2];
    const float* Wk   = (const float*)d_in[3];
    const float* bk   = (const float*)d_in[4];
    const float* Wv   = (const float*)d_in[5];
    const float* bv   = (const float*)d_in[6];
    const float* Wo   = (const float*)d_in[7];
    const float* bo   = (const float*)d_in[8];
    const float* gate = (const float*)d_in[9];
    float* out = (float*)d_out;

    char* p = (char*)d_ws;
    unsigned short* Xb   = (unsigned short*)p;  p += (size_t)MTOT*DM*2;
    unsigned short* Wqkv = (unsigned short*)p;  p += (size_t)3*DM*DM*2;
    unsigned short* Qb   = (unsigned short*)p;  p += (size_t)BB*NH*TT*HD*2;
    unsigned short* Kb   = (unsigned short*)p;  p += (size_t)BB*NH*TT*HD*2;
    unsigned short* Vtb  = (unsigned short*)p;  p += (size_t)BB*NH*TT*HD*2;
    unsigned short* A2   = (unsigned short*)p;  p += (size_t)MTOT*DM*2;
    unsigned short* Wob  = (unsigned short*)p;  p += (size_t)DM*DM*2;
    float*          bio  = (float*)p;           p += (size_t)DM*4;
    float*          Opart= (float*)p;           p += (size_t)2*OP_STRIDE*4;
    float*          lpart= (float*)p;           p += (size_t)2*LP_STRIDE*4;

    k_prep     <<<6723, 256, 0, stream>>>(x, Wq, Wk, Wv, Wo, bo, gate, Xb, Wqkv, Wob, bio);
    k_gemm_qkv <<<dim3((3*DM)/128, MTOT/128), 256, 0, stream>>>(Xb, Wqkv, bq, bk, bv, Qb, Kb, Vtb);
    k_flash    <<<dim3(BB*NH, TT/128, 2), 256, 0, stream>>>(Qb, Kb, Vtb, Opart, lpart);
    k_comb     <<<MTOT/4, 256, 0, stream>>>(Opart, lpart, A2);
    k_gemm_out <<<dim3(DM/128, MTOT/128), 256, 0, stream>>>(A2, Wob, bio, out);
}